// Round 6
// baseline (305.092 us; speedup 1.0000x reference)
//
#include <hip/hip_runtime.h>

// LlamaAttention_7352984010786 — Round 6: fp32 OUTPUT fix.
//
// Root cause of r3-r5 (~1.5 decorrelated absmax): the reference returns
// float32, so d_out is float* (per harness docs: "else float*"); I was
// writing packed bf16 halfwords -> harness fp32 word i = my element 2i+1 in
// position i -> right scale, permuted -> predicted absmax 5.43*sqrt(2)*0.193
// = 1.48, observed 1.51/1.51/1.45. The assert label's "(bf16," is a
// HARDCODED string, not a dtype indicator. Inputs fp32 (r2 NaN proof),
// documented dict order [x, Wq, Wk, Wv, Wo] restored (r3/r4 mapping was
// right all along).
//
// Algebra (verified + ref-max consistent): rope overwrites q/k; softmax(rr^T)
// Toeplitz, diag gap >= 10.5 => softmax == I to ~2.7e-5. out = (x@Wv^T)@Wo^T.
//
// Kernel: r4's fused VALU GEMM (known to execute cleanly), all-fp32:
// per-32-row stripe: V[32,256] = x@Wv^T (LDS, fp32), out = V@Wo^T, float4 stores.

typedef __attribute__((ext_vector_type(4))) float float4v;

#define XS_STR 36    // xs[16][36]  k-major x chunk (32 rows + pad)
#define WS_STR 260   // ws[16][260] k-major weight chunk (256 n + pad)
#define VS_STR 260   // vs[32][260] row-major V stripe, fp32

// x:[16384,768] f32  Wv:[256,768] f32  Wo:[768,256] f32  out:[16384,768] f32
__global__ __launch_bounds__(256, 2)
void fused_valu(const float* __restrict__ x, const float* __restrict__ Wv,
                const float* __restrict__ Wo, float* __restrict__ out) {
  __shared__ __align__(16) float xs[16 * XS_STR];   //  2.3 KB
  __shared__ __align__(16) float ws[16 * WS_STR];   // 16.6 KB
  __shared__ __align__(16) float vs[32 * VS_STR];   // 33.3 KB  (52.2 KB total)

  const int tid = threadIdx.x;
  const int tr  = tid >> 5;     // 0..7  -> rows tr*4 .. tr*4+3
  const int tc  = tid & 31;     // 0..31 -> cols tc*8 .. tc*8+7
  const int r64 = tid >> 2;     // 0..63 (weight staging)
  const int c4  = tid & 3;      // float4 slot within 16-wide k chunk
  const int row0 = blockIdx.x * 32;

  float acc[4][8];
#pragma unroll
  for (int i = 0; i < 4; ++i)
#pragma unroll
    for (int j = 0; j < 8; ++j) acc[i][j] = 0.f;

  // ---------------- phase 1: V[32][256] = x_stripe[32,768] @ Wv^T ----------
  for (int k0 = 0; k0 < 768; k0 += 16) {
    if (tid < 128) {            // 32 rows x 4 float4, transposed to k-major
      int rr = tid >> 2;        // 0..31
      float4v xv = *(const float4v*)(x + (size_t)(row0 + rr) * 768 + k0 + c4 * 4);
#pragma unroll
      for (int u = 0; u < 4; ++u) xs[(c4 * 4 + u) * XS_STR + rr] = xv[u];
    }
#pragma unroll
    for (int p = 0; p < 4; ++p) {
      int n = p * 64 + r64;     // 0..255
      float4v wv = *(const float4v*)(Wv + (size_t)n * 768 + k0 + c4 * 4);
#pragma unroll
      for (int u = 0; u < 4; ++u) ws[(c4 * 4 + u) * WS_STR + n] = wv[u];
    }
    __syncthreads();
#pragma unroll
    for (int kk = 0; kk < 16; ++kk) {
      float4v a  = *(const float4v*)(xs + kk * XS_STR + tr * 4);
      float4v b0 = *(const float4v*)(ws + kk * WS_STR + tc * 8);
      float4v b1 = *(const float4v*)(ws + kk * WS_STR + tc * 8 + 4);
#pragma unroll
      for (int i = 0; i < 4; ++i)
#pragma unroll
        for (int j = 0; j < 4; ++j) {
          acc[i][j]     += a[i] * b0[j];
          acc[i][j + 4] += a[i] * b1[j];
        }
    }
    __syncthreads();
  }

  // V -> LDS fp32, row-major
#pragma unroll
  for (int i = 0; i < 4; ++i)
#pragma unroll
    for (int j = 0; j < 8; ++j)
      vs[(tr * 4 + i) * VS_STR + tc * 8 + j] = acc[i][j];
  __syncthreads();

  // ---------------- phase 2: out_stripe[32,768] = V[32,256] @ Wo^T ---------
  for (int c = 0; c < 3; ++c) {
#pragma unroll
    for (int i = 0; i < 4; ++i)
#pragma unroll
      for (int j = 0; j < 8; ++j) acc[i][j] = 0.f;

    for (int k0 = 0; k0 < 256; k0 += 16) {
#pragma unroll
      for (int p = 0; p < 4; ++p) {
        int n = p * 64 + r64;
        float4v wv = *(const float4v*)(Wo + (size_t)(c * 256 + n) * 256 + k0 + c4 * 4);
#pragma unroll
        for (int u = 0; u < 4; ++u) ws[(c4 * 4 + u) * WS_STR + n] = wv[u];
      }
      __syncthreads();
#pragma unroll
      for (int kk = 0; kk < 16; ++kk) {
        float a[4];
#pragma unroll
        for (int i = 0; i < 4; ++i)              // same-address broadcast reads
          a[i] = vs[(tr * 4 + i) * VS_STR + k0 + kk];
        float4v b0 = *(const float4v*)(ws + kk * WS_STR + tc * 8);
        float4v b1 = *(const float4v*)(ws + kk * WS_STR + tc * 8 + 4);
#pragma unroll
        for (int i = 0; i < 4; ++i)
#pragma unroll
          for (int j = 0; j < 4; ++j) {
            acc[i][j]     += a[i] * b0[j];
            acc[i][j + 4] += a[i] * b1[j];
          }
      }
      __syncthreads();
    }

    // fp32 float4 stores, coalesced (8 contiguous cols per thread)
#pragma unroll
    for (int i = 0; i < 4; ++i) {
      float* o = out + (size_t)(row0 + tr * 4 + i) * 768 + c * 256 + tc * 8;
      *(float4v*)(o)     = (float4v){acc[i][0], acc[i][1], acc[i][2], acc[i][3]};
      *(float4v*)(o + 4) = (float4v){acc[i][4], acc[i][5], acc[i][6], acc[i][7]};
    }
  }
}

extern "C" void kernel_launch(void* const* d_in, const int* in_sizes, int n_in,
                              void* d_out, int out_size, void* d_ws, size_t ws_size,
                              hipStream_t stream) {
  (void)in_sizes; (void)n_in; (void)d_ws; (void)ws_size; (void)out_size;
  const float* x  = (const float*)d_in[0];  // [2*8192, 768]
  // d_in[1]=Wq, d_in[2]=Wk: dead (rope overwrites q,k)
  const float* Wv = (const float*)d_in[3];  // [256, 768]
  const float* Wo = (const float*)d_in[4];  // [768, 256]
  float* out = (float*)d_out;               // [16384, 768] fp32

  fused_valu<<<dim3(512), dim3(256), 0, stream>>>(x, Wv, Wo, out);
}

// Round 7
// 135.832 us; speedup vs baseline: 2.2461x; 2.2461x over previous
//
#include <hip/hip_runtime.h>

// LlamaAttention_7352984010786 — Round 7: bf16 MFMA version of the passing r6.
//
// out = (x @ Wv^T) @ Wo^T (softmax == I to ~3e-5, proven r0-r6; fp32 in/out,
// documented input order). r6 (VALU fp32) passed at 254 us, absmax 0.0039,
// VALUBusy 39%, 3.2e7 LDS conflicts. This round: 16x16x32 bf16 MFMA
// (m97-validated fragment mappings), 64-row stripe per block, 512 thr
// (2x4 wave grid), weights pre-tiled to bf16 [K/32][N][32] in d_ws so each
// k-tile stage is one contiguous coalesced 16 KB copy. fp32 epilogue.

typedef unsigned short u16;
typedef __attribute__((ext_vector_type(8))) short short8;   // 8 bf16 = 16 B
typedef __attribute__((ext_vector_type(4))) float float4v;

__device__ inline u16 f32_to_bf16(float f) {
  union { float f; unsigned int u; } v; v.f = f;
  unsigned int r = v.u + 0x7FFF + ((v.u >> 16) & 1);  // RNE
  return (u16)(r >> 16);
}

// ---------------- prep: Wv,Wo fp32 -> bf16, k-tiled [K/32][N][32] ----------
__global__ __launch_bounds__(256)
void prep_weights(const float* __restrict__ Wv, const float* __restrict__ Wo,
                  u16* __restrict__ wvt, u16* __restrict__ wot) {
  int id = blockIdx.x * 256 + threadIdx.x;          // 0..98303
  union { u16 h[4]; uint2 u; } p;
  if (id < 49152) {                                 // Wv: [256,768]
    int e = id * 4, n = e / 768, k = e - n * 768;
    float4v v = *(const float4v*)(Wv + (size_t)n * 768 + k);
    p.h[0] = f32_to_bf16(v[0]); p.h[1] = f32_to_bf16(v[1]);
    p.h[2] = f32_to_bf16(v[2]); p.h[3] = f32_to_bf16(v[3]);
    int t = k >> 5, kk = k & 31;
    *(uint2*)(wvt + ((t * 256 + n) * 32 + kk)) = p.u;
  } else {                                          // Wo: [768,256]
    int e = (id - 49152) * 4, n = e / 256, k = e - n * 256;
    float4v v = *(const float4v*)(Wo + (size_t)n * 256 + k);
    p.h[0] = f32_to_bf16(v[0]); p.h[1] = f32_to_bf16(v[1]);
    p.h[2] = f32_to_bf16(v[2]); p.h[3] = f32_to_bf16(v[3]);
    int t = k >> 5, kk = k & 31;
    *(uint2*)(wot + ((t * 768 + n) * 32 + kk)) = p.u;
  }
}

// ---------------- fused main ----------------------------------------------
// x:[16384,768] f32; weights via bf16 tiles (WS) or fp32 direct; out fp32.
template <bool WS>
__global__ __launch_bounds__(512, 1)
void fused_mfma(const float* __restrict__ x,
                const float* __restrict__ Wv, const float* __restrict__ Wo,
                const u16* __restrict__ wvt, const u16* __restrict__ wot,
                float* __restrict__ out) {
  __shared__ __align__(16) u16 As[64 * 32];     //  4 KB  x k-tile (m97 layout)
  __shared__ __align__(16) u16 Bs[256 * 32];    // 16 KB  weight k-tile
  __shared__ __align__(16) u16 Vs[64 * 264];    // 33 KB  V stripe (padded)

  const int tid = threadIdx.x;
  const int w  = tid >> 6, l = tid & 63;
  const int q  = l >> 4, mr = l & 15;
  const int wm = w & 1, wn = w >> 1;            // 2 (M) x 4 (N) wave grid
  const int row0 = blockIdx.x * 64;

  const int xr = tid >> 3, xg = (tid & 7) * 4;  // x staging: row, col-group
  const int wr = tid >> 1, wh = (tid & 1) * 16; // fp32 weight staging (fallback)

  float4v acc[2][4];
#pragma unroll
  for (int i = 0; i < 2; ++i)
#pragma unroll
    for (int j = 0; j < 4; ++j) acc[i][j] = (float4v){0.f, 0.f, 0.f, 0.f};

  // ---------- phase 1: V[64,256] = x_stripe @ Wv^T (K=768) ----------
  for (int kt = 0; kt < 24; ++kt) {
    const int k0 = kt * 32;
    { // x tile: fp32 -> bf16
      float4v v = *(const float4v*)(x + (size_t)(row0 + xr) * 768 + k0 + xg);
      union { u16 h[4]; uint2 u; } p;
      p.h[0] = f32_to_bf16(v[0]); p.h[1] = f32_to_bf16(v[1]);
      p.h[2] = f32_to_bf16(v[2]); p.h[3] = f32_to_bf16(v[3]);
      *(uint2*)(As + xr * 32 + xg) = p.u;
    }
    if (WS) { // contiguous 16 KB bf16 tile copy, fully coalesced
      const u16* g = wvt + (size_t)kt * (256 * 32);
#pragma unroll
      for (int p = 0; p < 2; ++p) {
        int c = tid + p * 512;
        *(short8*)(Bs + c * 8) = *(const short8*)(g + c * 8);
      }
    } else {  // fp32 weights direct + cvt
      const float* g = Wv + (size_t)wr * 768 + k0 + wh;
      union { u16 h[16]; short8 s[2]; } p;
#pragma unroll
      for (int u = 0; u < 4; ++u) {
        float4v v = *(const float4v*)(g + u * 4);
        p.h[u * 4 + 0] = f32_to_bf16(v[0]); p.h[u * 4 + 1] = f32_to_bf16(v[1]);
        p.h[u * 4 + 2] = f32_to_bf16(v[2]); p.h[u * 4 + 3] = f32_to_bf16(v[3]);
      }
      *(short8*)(Bs + wr * 32 + wh) = p.s[0];
      *(short8*)(Bs + wr * 32 + wh + 8) = p.s[1];
    }
    __syncthreads();

    short8 a[2], b[4];
#pragma unroll
    for (int i = 0; i < 2; ++i)   // A[m = wm*32+i*16+mr][k = q*8 + j]
      a[i] = *(const short8*)(As + (wm * 32 + i * 16 + mr) * 32 + q * 8);
#pragma unroll
    for (int j = 0; j < 4; ++j)   // Bt[n = wn*64+j*16+mr][k]
      b[j] = *(const short8*)(Bs + (wn * 64 + j * 16 + mr) * 32 + q * 8);
#pragma unroll
    for (int i = 0; i < 2; ++i)
#pragma unroll
      for (int j = 0; j < 4; ++j)
        acc[i][j] = __builtin_amdgcn_mfma_f32_16x16x32_bf16(a[i], b[j], acc[i][j], 0, 0, 0);
    __syncthreads();
  }

  // V -> LDS bf16 (C/D: col = lane&15, row = quad*4 + reg; m89-verified)
#pragma unroll
  for (int i = 0; i < 2; ++i)
#pragma unroll
    for (int j = 0; j < 4; ++j) {
      int row = wm * 32 + i * 16 + q * 4;
      int col = wn * 64 + j * 16 + mr;
#pragma unroll
      for (int r = 0; r < 4; ++r)
        Vs[(row + r) * 264 + col] = f32_to_bf16(acc[i][j][r]);
    }
  __syncthreads();

  // ---------- phase 2: out_stripe[64,768] = V[64,256] @ Wo^T ----------
  for (int c = 0; c < 3; ++c) {
    float4v acc2[2][4];
#pragma unroll
    for (int i = 0; i < 2; ++i)
#pragma unroll
      for (int j = 0; j < 4; ++j) acc2[i][j] = (float4v){0.f, 0.f, 0.f, 0.f};

    for (int kt = 0; kt < 8; ++kt) {
      const int k0 = kt * 32;
      if (WS) {
        const u16* g = wot + ((size_t)kt * 768 + c * 256) * 32;
#pragma unroll
        for (int p = 0; p < 2; ++p) {
          int cc = tid + p * 512;
          *(short8*)(Bs + cc * 8) = *(const short8*)(g + cc * 8);
        }
      } else {
        const float* g = Wo + (size_t)(c * 256 + wr) * 256 + k0 + wh;
        union { u16 h[16]; short8 s[2]; } p;
#pragma unroll
        for (int u = 0; u < 4; ++u) {
          float4v v = *(const float4v*)(g + u * 4);
          p.h[u * 4 + 0] = f32_to_bf16(v[0]); p.h[u * 4 + 1] = f32_to_bf16(v[1]);
          p.h[u * 4 + 2] = f32_to_bf16(v[2]); p.h[u * 4 + 3] = f32_to_bf16(v[3]);
        }
        *(short8*)(Bs + wr * 32 + wh) = p.s[0];
        *(short8*)(Bs + wr * 32 + wh + 8) = p.s[1];
      }
      __syncthreads();

      short8 a[2], b[4];
#pragma unroll
      for (int i = 0; i < 2; ++i)
        a[i] = *(const short8*)(Vs + (wm * 32 + i * 16 + mr) * 264 + k0 + q * 8);
#pragma unroll
      for (int j = 0; j < 4; ++j)
        b[j] = *(const short8*)(Bs + (wn * 64 + j * 16 + mr) * 32 + q * 8);
#pragma unroll
      for (int i = 0; i < 2; ++i)
#pragma unroll
        for (int j = 0; j < 4; ++j)
          acc2[i][j] = __builtin_amdgcn_mfma_f32_16x16x32_bf16(a[i], b[j], acc2[i][j], 0, 0, 0);
      __syncthreads();
    }

    // fp32 epilogue stores (16-lane 64B row segments)
#pragma unroll
    for (int i = 0; i < 2; ++i)
#pragma unroll
      for (int j = 0; j < 4; ++j) {
        int row = row0 + wm * 32 + i * 16 + q * 4;
        int col = c * 256 + wn * 64 + j * 16 + mr;
#pragma unroll
        for (int r = 0; r < 4; ++r)
          out[(size_t)(row + r) * 768 + col] = acc2[i][j][r];
      }
  }
}

extern "C" void kernel_launch(void* const* d_in, const int* in_sizes, int n_in,
                              void* d_out, int out_size, void* d_ws, size_t ws_size,
                              hipStream_t stream) {
  (void)in_sizes; (void)n_in; (void)out_size;
  const float* x  = (const float*)d_in[0];  // [16384, 768]
  const float* Wv = (const float*)d_in[3];  // [256, 768]
  const float* Wo = (const float*)d_in[4];  // [768, 256]
  float* out = (float*)d_out;

  if (ws_size >= 786432) {                  // bf16 tiled weights in d_ws
    u16* wvt = (u16*)d_ws;                  // 196608 u16
    u16* wot = wvt + 196608;                // 196608 u16
    prep_weights<<<dim3(384), dim3(256), 0, stream>>>(Wv, Wo, wvt, wot);
    fused_mfma<true><<<dim3(256), dim3(512), 0, stream>>>(x, Wv, Wo, wvt, wot, out);
  } else {
    fused_mfma<false><<<dim3(256), dim3(512), 0, stream>>>(x, Wv, Wo, nullptr, nullptr, out);
  }
}